// Round 6
// baseline (832.425 us; speedup 1.0000x reference)
//
#include <hip/hip_runtime.h>

constexpr int N_ = 20000, E_ = 320000, G_ = 64;
constexpr int NHID = 128, M_ = 4;
constexpr float EPS = 1e-5f;

#define RFL(v) __builtin_amdgcn_readfirstlane(v)
#define RLF(v, l) __int_as_float(__builtin_amdgcn_readlane(__float_as_int(v), (l)))

// ---------- moments: column mean-sums (16) and raw second-moment sums (16x16) ----------
__global__ void k_moments(const float* __restrict__ A, int R,
                          float* __restrict__ oSum, float* __restrict__ oOut) {
  __shared__ float ls[64][16];
  int t = threadIdx.x;                 // 256
  int k = t >> 4, j = t & 15;
  float accO = 0.f, accS = 0.f;
  for (int base = blockIdx.x * 64; base < R; base += gridDim.x * 64) {
    int rows = min(64, R - base);
    for (int i = t; i < rows * 16; i += 256) ls[i >> 4][i & 15] = A[base * 16 + i];
    __syncthreads();
    for (int r = 0; r < rows; ++r) accO += ls[r][k] * ls[r][j];
    if (t < 16) { for (int r = 0; r < rows; ++r) accS += ls[r][t]; }
    __syncthreads();
  }
  atomicAdd(&oOut[t], accO);
  if (t < 16) atomicAdd(&oSum[t], accS);
}

// ---------- fold BN into the 16->128 encoders (input enc + 3 edge encs) ----------
__global__ __launch_bounds__(512) void k_fold(
    const float* __restrict__ momNs, const float* __restrict__ momNo,
    const float* __restrict__ momEs, const float* __restrict__ momEo,
    const float* __restrict__ W_in, const float* __restrict__ b_in,
    const float* __restrict__ g_in, const float* __restrict__ bt_in,
    const float* __restrict__ W_e, const float* __restrict__ b_e,
    const float* __restrict__ g_e, const float* __restrict__ bt_e,
    float* __restrict__ Wf_in, float* __restrict__ bf_in,
    float* __restrict__ Wf_e, float* __restrict__ bf_e) {
  __shared__ float mN[16], oN[256], mE[16], oE[256];
  int t = threadIdx.x;
  if (t < 16) { mN[t] = momNs[t] * (1.f / N_); mE[t] = momEs[t] * (1.f / E_); }
  for (int i = t; i < 256; i += 512) { oN[i] = momNo[i] * (1.f / N_); oE[i] = momEo[i] * (1.f / E_); }
  __syncthreads();
  const float *m, *mo, *wrow; float bb, ggv, btv; float *wout, *boutp;
  if (t < 128) {
    m = mN; mo = oN; wrow = W_in + t * 16; bb = b_in[t]; ggv = g_in[t]; btv = bt_in[t];
    wout = Wf_in + t * 16; boutp = bf_in + t;
  } else {
    int u = t - 128;  // u = l*128 + c, 0..383
    m = mE; mo = oE; wrow = W_e + u * 16; bb = b_e[u]; ggv = g_e[u]; btv = bt_e[u];
    wout = Wf_e + u * 16; boutp = bf_e + u;
  }
  float wl[16];
#pragma unroll
  for (int k = 0; k < 16; ++k) wl[k] = wrow[k];
  float wm = 0.f;
#pragma unroll
  for (int k = 0; k < 16; ++k) wm = fmaf(wl[k], m[k], wm);
  float mu = wm + bb;
  float ey2 = bb * bb + 2.f * bb * wm;
  for (int k = 0; k < 16; ++k) {
#pragma unroll
    for (int j = 0; j < 16; ++j) ey2 = fmaf(wl[k] * wl[j], mo[k * 16 + j], ey2);
  }
  float var = ey2 - mu * mu;
  float s = ggv * rsqrtf(var + EPS);
#pragma unroll
  for (int k = 0; k < 16; ++k) wout[k] = wl[k] * s;
  *boutp = (bb - mu) * s + btv;
}

// ---------- fused input encoder + Linear2 -> x0 (N,128,4); 4 nodes/block ----------
__global__ __launch_bounds__(128) void k_lin2(
    const float* __restrict__ xn, const float* __restrict__ addx,
    const float* __restrict__ Wf, const float* __restrict__ bf,
    const float* __restrict__ W2, const float* __restrict__ b2,
    float* __restrict__ X) {
  __shared__ float a[4][16];
  __shared__ float h[4][128];
  int c = threadIdx.x;
  int n0 = blockIdx.x * 4;
  if (c < 64) a[c >> 4][c & 15] = xn[n0 * 16 + c];
  __syncthreads();
  float wl[16];
  const float* w = Wf + c * 16;
#pragma unroll
  for (int k = 0; k < 16; ++k) wl[k] = w[k];
  float bfc = bf[c];
#pragma unroll
  for (int nd = 0; nd < 4; ++nd) {
    float acc = bfc;
#pragma unroll
    for (int k = 0; k < 16; ++k) acc = fmaf(a[nd][k], wl[k], acc);
    h[nd][c] = fmaxf(acc, 0.f);
  }
  __syncthreads();
  float b2c = b2[c];
  float mn[4] = {b2c, b2c, b2c, b2c};
#pragma unroll 4
  for (int k = 0; k < 128; ++k) {
    float wv = W2[k * 129 + c];
    mn[0] = fmaf(h[0][k], wv, mn[0]);
    mn[1] = fmaf(h[1][k], wv, mn[1]);
    mn[2] = fmaf(h[2][k], wv, mn[2]);
    mn[3] = fmaf(h[3][k], wv, mn[3]);
  }
  int ccb = (c & 31) * 4;
  float wr0 = W2[(ccb + 0) * 129 + 128], br0 = b2[ccb + 0];
  float wr1 = W2[(ccb + 1) * 129 + 128], br1 = b2[ccb + 1];
  float wr2 = W2[(ccb + 2) * 129 + 128], br2 = b2[ccb + 2];
  float wr3 = W2[(ccb + 3) * 129 + 128], br3 = b2[ccb + 3];
  float4* Xv = reinterpret_cast<float4*>(X);
#pragma unroll
  for (int nd = 0; nd < 4; ++nd) {
    int i = 4 * (n0 + nd) + (c >> 5);
    int id = i / N_;
    int ir = i - id * N_;
    float xr = addx[ir * 4 + id];
    float4 o;
    o.x = mn[nd] + xr * wr0 + br0;
    o.y = mn[nd] + xr * wr1 + br1;
    o.z = mn[nd] + xr * wr2 + br2;
    o.w = mn[nd] + xr * wr3 + br3;
    Xv[(size_t)(n0 + nd) * 128 + c] = o;
  }
}

// ---------- CSR build ----------
__global__ void k_hist(const int* __restrict__ ei, int* __restrict__ cnt) {
  int e = blockIdx.x * 256 + threadIdx.x;
  if (e < E_) atomicAdd(&cnt[ei[E_ + e]], 1);
}

// shuffle-based scan: wave-local scans + cross-wave LDS, 3 barriers/chunk
__global__ __launch_bounds__(1024) void k_scan(const int* __restrict__ cnt, int* __restrict__ off) {
  __shared__ int wsum[16];
  __shared__ int carrySh;
  int t = threadIdx.x, lane = t & 63, w = t >> 6;
  if (t == 0) carrySh = 0;
  __syncthreads();
  for (int base = 0; base < N_; base += 1024) {
    int v = (base + t < N_) ? cnt[base + t] : 0;
    int s = v;
#pragma unroll
    for (int ofs = 1; ofs < 64; ofs <<= 1) {
      int u = __shfl_up(s, ofs);
      if (lane >= ofs) s += u;
    }
    if (lane == 63) wsum[w] = s;
    int carry = carrySh;
    __syncthreads();
    int pre = 0, tot = 0;
#pragma unroll
    for (int ww = 0; ww < 16; ++ww) {
      int x = wsum[ww];
      pre += (ww < w) ? x : 0;
      tot += x;
    }
    if (base + t < N_) off[base + t] = carry + pre + s - v;
    __syncthreads();
    if (t == 0) carrySh = carry + tot;
    __syncthreads();
  }
  if (t == 0) off[N_] = carrySh;
}

__global__ void k_scatter(const int* __restrict__ ei, const int* __restrict__ off,
                          int* __restrict__ cur, int* __restrict__ csr) {
  int e = blockIdx.x * 256 + threadIdx.x;
  if (e < E_) {
    int d = ei[E_ + e];
    int pidx = atomicAdd(&cur[d], 1);
    csr[off[d] + pidx] = e;
  }
}

// ---------- pack W_conv for the phase-2 float4 layout ----------
// WT4 float4[cc*64+lane] = { W[lane][2cc], W[lane+64][2cc], W[lane][2cc+1], W[lane+64][2cc+1] }
__global__ void k_transp(const float* __restrict__ Wc, float* __restrict__ WT4) {
  int i = blockIdx.x * 256 + threadIdx.x;  // 3*128*128
  if (i >= 3 * 128 * 128) return;
  int l = i >> 14, rest = i & 16383;
  int o = rest >> 7, c = rest & 127;
  WT4[l * 16384 + ((c >> 1) * 64 + (o & 63)) * 4 + (c & 1) * 2 + (o >> 6)] = Wc[i];
}

// ---------- graph boundaries ----------
__global__ void k_init64(int* g) { g[threadIdx.x] = N_; }
__global__ void k_bound(const int* __restrict__ batch, int* __restrict__ gstart) {
  int n = blockIdx.x * 256 + threadIdx.x;
  if (n < N_) atomicMin(&gstart[batch[n]], n);
}
__global__ void k_bound2(const int* __restrict__ gstart, int* __restrict__ gend) {
  int g = threadIdx.x;
  int e = N_;
  for (int gg = g + 1; gg < 64; ++gg) { int s = gstart[gg]; if (s < N_) { e = s; break; } }
  gend[g] = e;
}

// ---------- fused: gather-aggregate (on-the-fly edge encoder) + conv GEMM + BN stats ----------
// 512 threads = 8 waves, one node per wave; W_conv staged in LDS.
// __launch_bounds__(512, 4): 4 waves/EU -> 2 blocks/CU (matches the 72KB-LDS limit),
// forces VGPR <= 128 so the gather phase keeps 16 waves/CU of latency hiding.
// 3-stage data pipeline + 6-deep index queue; tails branch-free via clamped prefetch.
__global__ __launch_bounds__(512, 4) void k_aggemm(
    const float* __restrict__ X, const int* __restrict__ ei,
    const float* __restrict__ attr,
    const int* __restrict__ off, const int* __restrict__ csr,
    const float* __restrict__ Wf, const float* __restrict__ bf,
    const float* __restrict__ WT4,
    float* __restrict__ H3, float* __restrict__ bnsum, float* __restrict__ bnsumsq) {
  __shared__ float lW[16384];       // 64 KB: the packed W_conv layer
  __shared__ float red[512][4];     // 8 KB: BN3 partial sums
  int t = threadIdx.x;
  int lane = t & 63;
  int n = blockIdx.x * 8 + (t >> 6);     // grid is exactly N/8 blocks
  // stage W_conv into LDS (linear copy, layout preserved)
  {
    const float4* Wg = reinterpret_cast<const float4*>(WT4);
    float4* lW4 = reinterpret_cast<float4*>(lW);
#pragma unroll
    for (int i = 0; i < 8; ++i) lW4[t + i * 512] = Wg[t + i * 512];
  }
  // edge-encoder weights for this lane's two channels
  float w0[16], w1[16];
#pragma unroll
  for (int k = 0; k < 16; ++k) { w0[k] = Wf[lane * 16 + k]; w1[k] = Wf[(lane + 64) * 16 + k]; }
  float b0 = bf[lane], b1 = bf[lane + 64];
  const float4* Xv = reinterpret_cast<const float4*>(X);
  const float4* Av = reinterpret_cast<const float4*>(attr);
  float4 acc0 = Xv[(size_t)n * 128 + lane];
  float4 acc1 = Xv[(size_t)n * 128 + 64 + lane];
  __syncthreads();                  // staging complete (W only needed in phase 2)

  int qs = RFL(off[n]);
  int qe = RFL(off[n + 1]);
  if (qs < qe) {
    int last = qe - 1;
#define IDX(Q, EV, SV) { int qq_ = (Q) < last ? (Q) : last; EV = RFL(csr[qq_]); SV = RFL(ei[EV]); }
#define LOADP(SV, EV, X0, X1, AV) \
    X0 = Xv[(size_t)(SV) * 128 + lane]; \
    X1 = Xv[(size_t)(SV) * 128 + 64 + lane]; \
    AV = Av[(size_t)(EV) * 4 + (lane & 3)];
#define ETERM(AVV, CMP, LN, K) { float as_ = RLF(AVV.CMP, LN); \
    ee0 = fmaf(as_, w0[K], ee0); ee1 = fmaf(as_, w1[K], ee1); }
#define EDGE(X0, X1, AV) { \
    float ee0 = b0, ee1 = b1; \
    ETERM(AV, x, 0, 0)  ETERM(AV, y, 0, 1)  ETERM(AV, z, 0, 2)  ETERM(AV, w, 0, 3) \
    ETERM(AV, x, 1, 4)  ETERM(AV, y, 1, 5)  ETERM(AV, z, 1, 6)  ETERM(AV, w, 1, 7) \
    ETERM(AV, x, 2, 8)  ETERM(AV, y, 2, 9)  ETERM(AV, z, 2, 10) ETERM(AV, w, 2, 11) \
    ETERM(AV, x, 3, 12) ETERM(AV, y, 3, 13) ETERM(AV, z, 3, 14) ETERM(AV, w, 3, 15) \
    ee0 = fmaxf(ee0, 0.f); ee1 = fmaxf(ee1, 0.f); \
    acc0.x += fmaxf(X0.x + ee0, 0.f); acc0.y += fmaxf(X0.y + ee0, 0.f); \
    acc0.z += fmaxf(X0.z + ee0, 0.f); acc0.w += fmaxf(X0.w + ee0, 0.f); \
    acc1.x += fmaxf(X1.x + ee1, 0.f); acc1.y += fmaxf(X1.y + ee1, 0.f); \
    acc1.z += fmaxf(X1.z + ee1, 0.f); acc1.w += fmaxf(X1.w + ee1, 0.f); }
    // index queue: 6 deep (edges q..q+5)
    int e0, s0, e1, s1, e2, s2, e3, s3, e4, s4, e5, s5;
    IDX(qs,     e0, s0); IDX(qs + 1, e1, s1); IDX(qs + 2, e2, s2);
    IDX(qs + 3, e3, s3); IDX(qs + 4, e4, s4); IDX(qs + 5, e5, s5);
    // data stages
    float4 x00, x01, av0, x10, x11, av1, x20, x21, av2;
    LOADP(s0, e0, x00, x01, av0);
    LOADP(s1, e1, x10, x11, av1);
    LOADP(s2, e2, x20, x21, av2);
    for (int q = qs; q < qe; q += 3) {
      int n0i, n0s, n1i, n1s, n2i, n2s;
      IDX(q + 6, n0i, n0s); IDX(q + 7, n1i, n1s); IDX(q + 8, n2i, n2s);
      EDGE(x00, x01, av0);
      LOADP(s3, e3, x00, x01, av0);          // data for edge q+3
      if (q + 1 < qe) { EDGE(x10, x11, av1); }
      LOADP(s4, e4, x10, x11, av1);          // data for edge q+4
      if (q + 2 < qe) { EDGE(x20, x21, av2); }
      LOADP(s5, e5, x20, x21, av2);          // data for edge q+5
      // shift index queue
      e0 = e3; s0 = s3; e1 = e4; s1 = s4; e2 = e5; s2 = s5;
      e3 = n0i; s3 = n0s; e4 = n1i; s4 = n1s; e5 = n2i; s5 = n2s;
    }
#undef EDGE
#undef ETERM
#undef LOADP
#undef IDX
  }
  // phase 2: h3[o,m] = sum_c z[c,m]*W[o,c]; z broadcast via readlane, W from LDS
  float4 ha = {0, 0, 0, 0}, hb = {0, 0, 0, 0};
  const float4* Wv = reinterpret_cast<const float4*>(lW);
#pragma unroll 4
  for (int cc = 0; cc < 32; ++cc) {
    float4 wv = Wv[cc * 64 + lane];
    int l0 = 2 * cc, l1 = 2 * cc + 1;
    float za0 = RLF(acc0.x, l0), za1 = RLF(acc0.y, l0), za2 = RLF(acc0.z, l0), za3 = RLF(acc0.w, l0);
    float zb0 = RLF(acc0.x, l1), zb1 = RLF(acc0.y, l1), zb2 = RLF(acc0.z, l1), zb3 = RLF(acc0.w, l1);
    ha.x = fmaf(za0, wv.x, ha.x); ha.y = fmaf(za1, wv.x, ha.y); ha.z = fmaf(za2, wv.x, ha.z); ha.w = fmaf(za3, wv.x, ha.w);
    hb.x = fmaf(za0, wv.y, hb.x); hb.y = fmaf(za1, wv.y, hb.y); hb.z = fmaf(za2, wv.y, hb.z); hb.w = fmaf(za3, wv.y, hb.w);
    ha.x = fmaf(zb0, wv.z, ha.x); ha.y = fmaf(zb1, wv.z, ha.y); ha.z = fmaf(zb2, wv.z, ha.z); ha.w = fmaf(zb3, wv.z, ha.w);
    hb.x = fmaf(zb0, wv.w, hb.x); hb.y = fmaf(zb1, wv.w, hb.y); hb.z = fmaf(zb2, wv.w, hb.z); hb.w = fmaf(zb3, wv.w, hb.w);
  }
#pragma unroll 4
  for (int cc = 32; cc < 64; ++cc) {
    float4 wv = Wv[cc * 64 + lane];
    int l0 = 2 * cc - 64, l1 = 2 * cc - 63;
    float za0 = RLF(acc1.x, l0), za1 = RLF(acc1.y, l0), za2 = RLF(acc1.z, l0), za3 = RLF(acc1.w, l0);
    float zb0 = RLF(acc1.x, l1), zb1 = RLF(acc1.y, l1), zb2 = RLF(acc1.z, l1), zb3 = RLF(acc1.w, l1);
    ha.x = fmaf(za0, wv.x, ha.x); ha.y = fmaf(za1, wv.x, ha.y); ha.z = fmaf(za2, wv.x, ha.z); ha.w = fmaf(za3, wv.x, ha.w);
    hb.x = fmaf(za0, wv.y, hb.x); hb.y = fmaf(za1, wv.y, hb.y); hb.z = fmaf(za2, wv.y, hb.z); hb.w = fmaf(za3, wv.y, hb.w);
    ha.x = fmaf(zb0, wv.z, ha.x); ha.y = fmaf(zb1, wv.z, ha.y); ha.z = fmaf(zb2, wv.z, ha.z); ha.w = fmaf(zb3, wv.z, ha.w);
    hb.x = fmaf(zb0, wv.w, hb.x); hb.y = fmaf(zb1, wv.w, hb.y); hb.z = fmaf(zb2, wv.w, hb.z); hb.w = fmaf(zb3, wv.w, hb.w);
  }
  float4* Hv = reinterpret_cast<float4*>(H3);
  Hv[(size_t)n * 128 + lane] = ha;
  Hv[(size_t)n * 128 + 64 + lane] = hb;
  // BN3 stats: channel o=lane (ha), o=lane+64 (hb)
  red[t][0] = ha.x + ha.y + ha.z + ha.w;
  red[t][1] = ha.x * ha.x + ha.y * ha.y + ha.z * ha.z + ha.w * ha.w;
  red[t][2] = hb.x + hb.y + hb.z + hb.w;
  red[t][3] = hb.x * hb.x + hb.y * hb.y + hb.z * hb.z + hb.w * hb.w;
  __syncthreads();
  if (t < 256) {
    int ch = t >> 1, st = t & 1;
    int ln = ch & 63, pr = ch >> 6;
    float v = 0.f;
#pragma unroll
    for (int w8 = 0; w8 < 8; ++w8) v += red[w8 * 64 + ln][pr * 2 + st];
    if (st == 0) atomicAdd(&bnsum[ch], v); else atomicAdd(&bnsumsq[ch], v);
  }
}

// ---------- BN3 + relu + residual (in place on X) ----------
__global__ void k_bnres(const float* __restrict__ H3, float* __restrict__ X,
                        const float* __restrict__ bnsum, const float* __restrict__ bnsumsq,
                        const float* __restrict__ gg, const float* __restrict__ bb) {
  constexpr float inv = 1.f / (N_ * 4);
  const float4* Hv = (const float4*)H3;
  float4* Xv = (float4*)X;
  for (int i = blockIdx.x * 256 + threadIdx.x; i < N_ * 128; i += gridDim.x * 256) {
    int o = i & 127;
    float mu = bnsum[o] * inv;
    float var = bnsumsq[o] * inv - mu * mu;
    float sc = gg[o] * rsqrtf(var + EPS);
    float sh = bb[o] - mu * sc;
    float4 h = Hv[i];
    float4 x = Xv[i];
    x.x += fmaxf(fmaf(h.x, sc, sh), 0.f);
    x.y += fmaxf(fmaf(h.y, sc, sh), 0.f);
    x.z += fmaxf(fmaf(h.z, sc, sh), 0.f);
    x.w += fmaxf(fmaf(h.w, sc, sh), 0.f);
    Xv[i] = x;
  }
}

// ---------- pooling ----------
__global__ void k_pool(const float* __restrict__ X, const int* __restrict__ gstart,
                       const int* __restrict__ gend, float* __restrict__ xg) {
  int g = blockIdx.x >> 3, sl = blockIdx.x & 7;
  int t = threadIdx.x;
  int s = gstart[g], e = gend[g];
  float a0 = 0.f, a1 = 0.f;
  for (int n = s + sl; n < e; n += 8) {
    a0 += X[(size_t)n * 512 + t];
    a1 += X[(size_t)n * 512 + t + 256];
  }
  atomicAdd(&xg[g * 512 + t], a0);
  atomicAdd(&xg[g * 512 + t + 256], a1);
}

// ---------- output head ----------
__global__ void k_head1(const float* __restrict__ xg, const float* __restrict__ W1,
                        const float* __restrict__ b1, float* __restrict__ o1p,
                        float* __restrict__ hsum, float* __restrict__ hsumsq) {
  int t = threadIdx.x;
  int r = blockIdx.x * 4 + (t >> 6), c = t & 63;
  const float* xr = xg + r * 128;
  const float* w = W1 + c * 128;
  float acc = b1[c];
#pragma unroll 8
  for (int k = 0; k < 128; ++k) acc = fmaf(xr[k], w[k], acc);
  o1p[r * 64 + c] = acc;
  atomicAdd(&hsum[c], acc);
  atomicAdd(&hsumsq[c], acc * acc);
}

__global__ void k_head2(const float* __restrict__ o1p, const float* __restrict__ hsum,
                        const float* __restrict__ hsumsq, const float* __restrict__ g_out,
                        const float* __restrict__ bt_out, const float* __restrict__ W2,
                        const float* __restrict__ b2, float* __restrict__ out) {
  __shared__ float s1[4][64];
  __shared__ float s2[4][64];
  int g = blockIdx.x, j = threadIdx.x;
  float mu = hsum[j] * (1.f / 256.f);
  float var = hsumsq[j] * (1.f / 256.f) - mu * mu;
  float sc = g_out[j] * rsqrtf(var + EPS);
  float sh = bt_out[j] - mu * sc;
  for (int r = 0; r < 4; ++r) {
    float v = o1p[(4 * g + r) * 64 + j];
    s1[r][j] = fmaxf(fmaf(v, sc, sh), 0.f);
  }
  __syncthreads();
  for (int r = 0; r < 4; ++r) {
    float acc = b2[j];
#pragma unroll 8
    for (int k = 0; k < 64; ++k) acc = fmaf(s1[r][k], W2[j * 64 + k], acc);
    s2[r][j] = acc;
  }
  __syncthreads();
  float o = 0.f;
#pragma unroll
  for (int k = 0; k < 4; ++k) {
    int t4 = 4 * j + k;
    o += s2[t4 >> 6][t4 & 63];
  }
  out[g * 64 + j] = o * 0.25f;
}

extern "C" void kernel_launch(void* const* d_in, const int* in_sizes, int n_in,
                              void* d_out, int out_size, void* d_ws, size_t ws_size,
                              hipStream_t stream) {
  const float* x_node   = (const float*)d_in[0];
  const float* edge_attr= (const float*)d_in[1];
  const int*   edge_index=(const int*)d_in[2];
  const int*   batch    = (const int*)d_in[3];
  const float* addx     = (const float*)d_in[4];
  const float* W_in  = (const float*)d_in[5];
  const float* b_in  = (const float*)d_in[6];
  const float* g_in  = (const float*)d_in[7];
  const float* bt_in = (const float*)d_in[8];
  const float* W_l2  = (const float*)d_in[9];
  const float* b_l2  = (const float*)d_in[10];
  const float* W_edge  = (const float*)d_in[11];
  const float* b_edge  = (const float*)d_in[12];
  const float* g_edge  = (const float*)d_in[13];
  const float* bt_edge = (const float*)d_in[14];
  const float* W_conv  = (const float*)d_in[15];
  const float* g_norm  = (const float*)d_in[16];
  const float* bt_norm = (const float*)d_in[17];
  const float* W_out1  = (const float*)d_in[18];
  const float* b_out1  = (const float*)d_in[19];
  const float* g_out   = (const float*)d_in[20];
  const float* bt_out  = (const float*)d_in[21];
  const float* W_out2  = (const float*)d_in[22];
  const float* b_out2  = (const float*)d_in[23];
  float* out = (float*)d_out;

  char* base = (char*)d_ws;
  size_t p = 0;
  auto take = [&](size_t bytes) -> char* {
    char* r = base + p;
    p = (p + bytes + 255) & ~(size_t)255;
    return r;
  };
  int*   csr_cnt  = (int*)take((size_t)N_ * 4);
  int*   csr_cur  = (int*)take((size_t)N_ * 4);
  float* momNs    = (float*)take(16 * 4);
  float* momNo    = (float*)take(256 * 4);
  float* momEs    = (float*)take(16 * 4);
  float* momEo    = (float*)take(256 * 4);
  float* bnsum    = (float*)take(3 * 128 * 4);
  float* bnsumsq  = (float*)take(3 * 128 * 4);
  float* xg       = (float*)take(64 * 512 * 4);
  float* hsum     = (float*)take(64 * 4);
  float* hsumsq   = (float*)take(64 * 4);
  size_t zeroEnd = p;
  int*   gstart   = (int*)take(64 * 4);
  int*   gend     = (int*)take(64 * 4);
  int*   csr_off  = (int*)take((size_t)(N_ + 1) * 4);
  int*   csr_edges= (int*)take((size_t)E_ * 4);
  float* Wf_in    = (float*)take(128 * 16 * 4);
  float* bf_in    = (float*)take(128 * 4);
  float* Wf_e     = (float*)take(3 * 128 * 16 * 4);
  float* bf_e     = (float*)take(3 * 128 * 4);
  float* WT4      = (float*)take(3 * 128 * 128 * 4);
  float* o1p      = (float*)take(256 * 64 * 4);
  float* A        = (float*)take((size_t)N_ * 512 * 4);
  float* B        = (float*)take((size_t)N_ * 512 * 4);

  hipMemsetAsync(d_ws, 0, zeroEnd, stream);
  k_init64<<<1, 64, 0, stream>>>(gstart);
  k_moments<<<320, 256, 0, stream>>>(x_node, N_, momNs, momNo);
  k_moments<<<2048, 256, 0, stream>>>(edge_attr, E_, momEs, momEo);
  k_fold<<<1, 512, 0, stream>>>(momNs, momNo, momEs, momEo,
                                W_in, b_in, g_in, bt_in,
                                W_edge, b_edge, g_edge, bt_edge,
                                Wf_in, bf_in, Wf_e, bf_e);
  k_lin2<<<N_ / 4, 128, 0, stream>>>(x_node, addx, Wf_in, bf_in, W_l2, b_l2, A);
  k_hist<<<1250, 256, 0, stream>>>(edge_index, csr_cnt);
  k_scan<<<1, 1024, 0, stream>>>(csr_cnt, csr_off);
  k_scatter<<<1250, 256, 0, stream>>>(edge_index, csr_off, csr_cur, csr_edges);
  k_transp<<<192, 256, 0, stream>>>(W_conv, WT4);
  k_bound<<<79, 256, 0, stream>>>(batch, gstart);
  k_bound2<<<1, 64, 0, stream>>>(gstart, gend);
  for (int l = 0; l < 3; ++l) {
    k_aggemm<<<N_ / 8, 512, 0, stream>>>(A, edge_index, edge_attr, csr_off, csr_edges,
                                         Wf_e + l * 128 * 16, bf_e + l * 128,
                                         WT4 + l * 16384, B,
                                         bnsum + l * 128, bnsumsq + l * 128);
    k_bnres<<<2048, 256, 0, stream>>>(B, A, bnsum + l * 128, bnsumsq + l * 128,
                                      g_norm + l * 128, bt_norm + l * 128);
  }
  k_pool<<<512, 256, 0, stream>>>(A, gstart, gend, xg);
  k_head1<<<64, 256, 0, stream>>>(xg, W_out1, b_out1, o1p, hsum, hsumsq);
  k_head2<<<64, 64, 0, stream>>>(o1p, hsum, hsumsq, g_out, bt_out, W_out2, b_out2, out);
  (void)in_sizes; (void)n_in; (void)out_size; (void)ws_size;
}